// Round 1
// baseline (737.454 us; speedup 1.0000x reference)
//
#include <hip/hip_runtime.h>

// Problem constants (fixed by setup_inputs)
#define BB 2
#define CC 256
#define HH 100
#define WW 100
#define NROI 512
#define KDIM 12544   // 49*256
#define FC 1024

typedef _Float16 half_t;
typedef _Float16 f16x8 __attribute__((ext_vector_type(8)));
typedef _Float16 f16x4 __attribute__((ext_vector_type(4)));
typedef float f32x4 __attribute__((ext_vector_type(4)));

// ---------------- feat (B,C,H,W) -> featT (B,H*W,C) ----------------
__global__ __launch_bounds__(256) void transpose_feat(const float* __restrict__ feat,
                                                      float* __restrict__ featT) {
  __shared__ float tile[32][33];
  int b = blockIdx.z;
  int hw0 = blockIdx.x * 32;
  int c0 = blockIdx.y * 32;
  int tx = threadIdx.x, ty = threadIdx.y;
  const float* fb = feat + (size_t)b * CC * (HH * WW);
#pragma unroll
  for (int i = 0; i < 4; i++) {
    int c = c0 + ty + i * 8;
    int hw = hw0 + tx;
    tile[ty + i * 8][tx] = (hw < HH * WW) ? fb[(size_t)c * (HH * WW) + hw] : 0.0f;
  }
  __syncthreads();
  float* ob = featT + (size_t)b * (HH * WW) * CC;
#pragma unroll
  for (int i = 0; i < 4; i++) {
    int hw = hw0 + ty + i * 8;
    int c = c0 + tx;
    if (hw < HH * WW) ob[(size_t)hw * CC + c] = tile[tx][ty + i * 8];
  }
}

// ---- w1 (1024, 12544 with k=c*49+p) -> w1p fp16 (1024, 12544 with k'=p*256+c) ----
__global__ __launch_bounds__(256) void permute_w1(const float* __restrict__ w1,
                                                  half_t* __restrict__ w1p) {
  __shared__ float row[KDIM];  // 50176 B
  int j = blockIdx.x;
  const float* src = w1 + (size_t)j * KDIM;
  for (int i = threadIdx.x; i < KDIM; i += 256) row[i] = src[i];
  __syncthreads();
  half_t* dst = w1p + (size_t)j * KDIM;
  for (int o = threadIdx.x; o < KDIM; o += 256) {
    int c = o & 255, p = o >> 8;
    dst[o] = (half_t)row[c * 49 + p];   // LDS stride 49 -> odd bank stride, conflict-free
  }
}

// ---------------- fp32 -> fp16 convert (w2) ----------------
__global__ __launch_bounds__(256) void convert_f32_f16(const float* __restrict__ in,
                                                       half_t* __restrict__ out, int n) {
  int i4 = (blockIdx.x * 256 + threadIdx.x) * 4;
  if (i4 < n) {
    float4 v = *(const float4*)(in + i4);
    f16x4 o;
    o[0] = (half_t)v.x; o[1] = (half_t)v.y; o[2] = (half_t)v.z; o[3] = (half_t)v.w;
    *(f16x4*)(out + i4) = o;
  }
}

// ---------------- deformable PSROI pooling ----------------
// grid: NROI*7 (block = (n, ph)), 256 threads = one channel each.
// PASS2=false: writes x fp16 in (N, 49, 256) layout (k'=p*256+c) for GEMM1.
// PASS2=true : reads om (N,147): [0:49]=tx, [49:98]=ty, [98:147]=mask logits;
//              writes out (N,C,7,7) fp32, multiplied by sigmoid(mask).
template <bool PASS2>
__global__ __launch_bounds__(256) void pool_kernel(const float* __restrict__ featT,
                                                   const float* __restrict__ rois,
                                                   const float* __restrict__ om,
                                                   half_t* __restrict__ xout,
                                                   float* __restrict__ out) {
  int bid = blockIdx.x;
  int n = bid / 7, ph = bid % 7;
  int c = threadIdx.x;
  const float* r = rois + n * 5;
  int b = (int)r[0];
  float rsw = rintf(r[1]) * 0.0625f - 0.5f;     // rintf = round-half-even = jnp.round
  float rsh = rintf(r[2]) * 0.0625f - 0.5f;
  float rew = (rintf(r[3]) + 1.0f) * 0.0625f - 0.5f;
  float reh = (rintf(r[4]) + 1.0f) * 0.0625f - 0.5f;
  float roi_w = fmaxf(rew - rsw, 0.1f);
  float roi_h = fmaxf(reh - rsh, 0.1f);
  float bin_h = roi_h / 7.0f;
  float bin_w = roi_w / 7.0f;
  float sub_h = bin_h * 0.25f;
  float sub_w = bin_w * 0.25f;
  const float* fb = featT + (size_t)b * (HH * WW) * CC;

  for (int pw = 0; pw < 7; pw++) {
    float tx = 0.0f, ty = 0.0f, mask = 1.0f;
    if (PASS2) {
      int part_h = (int)floorf((float)ph / 7.0f * 7.0f);  // match reference exactly
      int part_w = (int)floorf((float)pw / 7.0f * 7.0f);
      const float* on = om + n * 147;
      tx = on[part_h * 7 + part_w] * 0.1f;
      ty = on[49 + part_h * 7 + part_w] * 0.1f;
      float mv = on[98 + ph * 7 + pw];
      mask = 1.0f / (1.0f + expf(-mv));
    }
    float hst = (float)ph * bin_h + rsh + ty * roi_h;
    float wst = (float)pw * bin_w + rsw + tx * roi_w;
    float acc = 0.0f;
    int cnt = 0;
    for (int s = 0; s < 16; s++) {
      float h = hst + (float)(s >> 2) * sub_h;
      float w = wst + (float)(s & 3) * sub_w;
      if (w >= -0.5f && w <= (float)WW - 0.5f && h >= -0.5f && h <= (float)HH - 0.5f) {
        float hc = fminf(fmaxf(h, 0.0f), (float)(HH - 1));
        float wc = fminf(fmaxf(w, 0.0f), (float)(WW - 1));
        int h0 = (int)hc;             // hc >= 0 -> trunc == floor
        int w0 = (int)wc;
        int h1 = min(h0 + 1, HH - 1);
        int w1i = min(w0 + 1, WW - 1);
        float lh = hc - (float)h0;
        float lw = wc - (float)w0;
        float v00 = fb[((size_t)(h0 * WW + w0)) * CC + c];
        float v01 = fb[((size_t)(h0 * WW + w1i)) * CC + c];
        float v10 = fb[((size_t)(h1 * WW + w0)) * CC + c];
        float v11 = fb[((size_t)(h1 * WW + w1i)) * CC + c];
        acc += (v00 * (1.0f - lh) + v10 * lh) * (1.0f - lw) +
               (v01 * (1.0f - lh) + v11 * lh) * lw;
        cnt++;
      }
    }
    float val = (cnt > 0) ? acc / (float)cnt : 0.0f;
    int p = ph * 7 + pw;
    if (PASS2) {
      out[((size_t)(n * CC + c)) * 49 + p] = val * mask;
    } else {
      xout[(size_t)n * KDIM + p * CC + c] = (half_t)val;
    }
  }
}

// ---------------- fp16 MFMA GEMM: C = A(MxK) * B(NxK)^T + bias [, relu] ----------------
// 64x64 tile, BK=64, 4 waves each computing 32x32 via 2x2 of 16x16x32 MFMA.
template <bool OUT_F16, bool RELU>
__global__ __launch_bounds__(256) void gemm_bt(const half_t* __restrict__ A,
                                               const half_t* __restrict__ B,
                                               const float* __restrict__ bias,
                                               void* __restrict__ Cp,
                                               int M, int N, int K) {
  __shared__ half_t As[64 * 72];  // +8 pad: 144B row stride, 16B-aligned, 2-way-max banks
  __shared__ half_t Bs[64 * 72];
  const int m0 = blockIdx.x * 64;
  const int n0 = blockIdx.y * 64;
  const int tid = threadIdx.x;
  const int lane = tid & 63;
  const int wave = tid >> 6;
  const int wm = (wave & 1) * 32;
  const int wn = (wave >> 1) * 32;
  const int lrow = tid >> 3;          // 0..31
  const int lcol = (tid & 7) * 8;     // 0,8,..,56
  const int fr = lane & 15;
  const int fk = (lane >> 4) * 8;
  f32x4 acc[2][2] = {};
  const half_t* Arow0 = A + (size_t)(m0 + lrow) * K + lcol;
  const half_t* Arow1 = Arow0 + (size_t)32 * K;
  const half_t* Brow0 = B + (size_t)(n0 + lrow) * K + lcol;
  const half_t* Brow1 = Brow0 + (size_t)32 * K;

  for (int k0 = 0; k0 < K; k0 += 64) {
    *(uint4*)&As[lrow * 72 + lcol] = *(const uint4*)(Arow0 + k0);
    *(uint4*)&As[(lrow + 32) * 72 + lcol] = *(const uint4*)(Arow1 + k0);
    *(uint4*)&Bs[lrow * 72 + lcol] = *(const uint4*)(Brow0 + k0);
    *(uint4*)&Bs[(lrow + 32) * 72 + lcol] = *(const uint4*)(Brow1 + k0);
    __syncthreads();
#pragma unroll
    for (int ks = 0; ks < 2; ks++) {
      f16x8 a0 = *(const f16x8*)&As[(wm + fr) * 72 + fk + ks * 32];
      f16x8 a1 = *(const f16x8*)&As[(wm + 16 + fr) * 72 + fk + ks * 32];
      f16x8 b0 = *(const f16x8*)&Bs[(wn + fr) * 72 + fk + ks * 32];
      f16x8 b1 = *(const f16x8*)&Bs[(wn + 16 + fr) * 72 + fk + ks * 32];
      acc[0][0] = __builtin_amdgcn_mfma_f32_16x16x32_f16(a0, b0, acc[0][0], 0, 0, 0);
      acc[0][1] = __builtin_amdgcn_mfma_f32_16x16x32_f16(a0, b1, acc[0][1], 0, 0, 0);
      acc[1][0] = __builtin_amdgcn_mfma_f32_16x16x32_f16(a1, b0, acc[1][0], 0, 0, 0);
      acc[1][1] = __builtin_amdgcn_mfma_f32_16x16x32_f16(a1, b1, acc[1][1], 0, 0, 0);
    }
    __syncthreads();
  }
  // epilogue: C/D layout col=lane&15, row=(lane>>4)*4+reg  [measured m89/m91]
  const int orow = m0 + wm + (lane >> 4) * 4;
  const int ocol = n0 + wn + (lane & 15);
#pragma unroll
  for (int ti = 0; ti < 2; ti++) {
#pragma unroll
    for (int tj = 0; tj < 2; tj++) {
      int col = ocol + tj * 16;
      float bv = bias[col];
#pragma unroll
      for (int rr = 0; rr < 4; rr++) {
        int row = orow + ti * 16 + rr;
        float v = acc[ti][tj][rr] + bv;
        if (RELU) v = fmaxf(v, 0.0f);
        if (OUT_F16)
          ((half_t*)Cp)[(size_t)row * N + col] = (half_t)v;
        else
          ((float*)Cp)[(size_t)row * N + col] = v;
      }
    }
  }
}

// ---------------- fp32 GEMM3: om(N,147) = h2(N,1024) @ w3(147,1024)^T + b3 ----------------
__global__ __launch_bounds__(192) void gemm_small(const float* __restrict__ h2,
                                                  const float* __restrict__ w3,
                                                  const float* __restrict__ b3,
                                                  float* __restrict__ om) {
  __shared__ float hs[FC];
  int n = blockIdx.x;
  for (int k = threadIdx.x; k < FC; k += 192) hs[k] = h2[(size_t)n * FC + k];
  __syncthreads();
  int j = threadIdx.x;
  if (j < 147) {
    float acc = b3[j];
    const float* wr = w3 + (size_t)j * FC;
    for (int k = 0; k < FC; k += 4) {
      float4 wv = *(const float4*)(wr + k);
      acc += hs[k] * wv.x + hs[k + 1] * wv.y + hs[k + 2] * wv.z + hs[k + 3] * wv.w;
    }
    om[n * 147 + j] = acc;
  }
}

extern "C" void kernel_launch(void* const* d_in, const int* in_sizes, int n_in,
                              void* d_out, int out_size, void* d_ws, size_t ws_size,
                              hipStream_t stream) {
  const float* feat = (const float*)d_in[0];
  const float* rois = (const float*)d_in[1];
  const float* w1 = (const float*)d_in[2];
  const float* b1 = (const float*)d_in[3];
  const float* w2 = (const float*)d_in[4];
  const float* b2 = (const float*)d_in[5];
  const float* w3 = (const float*)d_in[6];
  const float* b3 = (const float*)d_in[7];
  float* out = (float*)d_out;
  char* ws = (char*)d_ws;

  // workspace carve (all 256B-aligned); total ~64.6 MB
  float* featT = (float*)ws;                          // 20,480,000 B
  half_t* xh   = (half_t*)(ws + 20480000);            // 12,845,056 B
  half_t* w1p  = (half_t*)(ws + 33325056);            // 25,690,112 B
  half_t* w2h  = (half_t*)(ws + 59015168);            //  2,097,152 B
  half_t* h1   = (half_t*)(ws + 61112320);            //  1,048,576 B
  float* h2    = (float*)(ws + 62160896);             //  2,097,152 B
  float* omb   = (float*)(ws + 64258048);             //    301,056 B

  transpose_feat<<<dim3(313, 8, 2), dim3(32, 8), 0, stream>>>(feat, featT);
  permute_w1<<<dim3(1024), dim3(256), 0, stream>>>(w1, w1p);
  convert_f32_f16<<<dim3(1024), dim3(256), 0, stream>>>(w2, w2h, FC * FC);
  pool_kernel<false><<<dim3(NROI * 7), dim3(256), 0, stream>>>(featT, rois, nullptr, xh, nullptr);
  gemm_bt<true, true><<<dim3(8, 16), dim3(256), 0, stream>>>(xh, w1p, b1, (void*)h1, NROI, FC, KDIM);
  gemm_bt<false, true><<<dim3(8, 16), dim3(256), 0, stream>>>(h1, w2h, b2, (void*)h2, NROI, FC, FC);
  gemm_small<<<dim3(NROI), dim3(192), 0, stream>>>(h2, w3, b3, omb);
  pool_kernel<true><<<dim3(NROI * 7), dim3(256), 0, stream>>>(featT, rois, omb, nullptr, out);
}

// Round 2
// 563.012 us; speedup vs baseline: 1.3098x; 1.3098x over previous
//
#include <hip/hip_runtime.h>

// Problem constants (fixed by setup_inputs)
#define BB 2
#define CC 256
#define HH 100
#define WW 100
#define NROI 512
#define KDIM 12544   // 49*256
#define FC 1024

typedef _Float16 half_t;
typedef _Float16 f16x8 __attribute__((ext_vector_type(8)));
typedef _Float16 f16x4 __attribute__((ext_vector_type(4)));
typedef float f32x4 __attribute__((ext_vector_type(4)));

// ---------------- feat (B,C,H,W) fp32 -> featT (B,H*W,C) fp16 ----------------
__global__ __launch_bounds__(256) void transpose_feat(const float* __restrict__ feat,
                                                      half_t* __restrict__ featT) {
  __shared__ float tile[32][33];
  int b = blockIdx.z;
  int hw0 = blockIdx.x * 32;
  int c0 = blockIdx.y * 32;
  int tx = threadIdx.x, ty = threadIdx.y;
  const float* fb = feat + (size_t)b * CC * (HH * WW);
#pragma unroll
  for (int i = 0; i < 4; i++) {
    int c = c0 + ty + i * 8;
    int hw = hw0 + tx;
    tile[ty + i * 8][tx] = (hw < HH * WW) ? fb[(size_t)c * (HH * WW) + hw] : 0.0f;
  }
  __syncthreads();
  half_t* ob = featT + (size_t)b * (HH * WW) * CC;
#pragma unroll
  for (int i = 0; i < 4; i++) {
    int hw = hw0 + ty + i * 8;
    int c = c0 + tx;
    if (hw < HH * WW) ob[(size_t)hw * CC + c] = (half_t)tile[tx][ty + i * 8];
  }
}

// ---- w1 (1024, 12544 with k=c*49+p) -> w1p fp16 (1024, 12544 with k'=p*256+c) ----
__global__ __launch_bounds__(256) void permute_w1(const float* __restrict__ w1,
                                                  half_t* __restrict__ w1p) {
  __shared__ float row[KDIM];  // 50176 B
  int j = blockIdx.x;
  const float* src = w1 + (size_t)j * KDIM;
  for (int i = threadIdx.x; i < KDIM; i += 256) row[i] = src[i];
  __syncthreads();
  half_t* dst = w1p + (size_t)j * KDIM;
  for (int o = threadIdx.x; o < KDIM; o += 256) {
    int c = o & 255, p = o >> 8;
    dst[o] = (half_t)row[c * 49 + p];   // LDS stride 49 -> odd bank stride, conflict-free
  }
}

// ---------------- fp32 -> fp16 convert (w2) ----------------
__global__ __launch_bounds__(256) void convert_f32_f16(const float* __restrict__ in,
                                                       half_t* __restrict__ out, int n) {
  int i4 = (blockIdx.x * 256 + threadIdx.x) * 4;
  if (i4 < n) {
    float4 v = *(const float4*)(in + i4);
    f16x4 o;
    o[0] = (half_t)v.x; o[1] = (half_t)v.y; o[2] = (half_t)v.z; o[3] = (half_t)v.w;
    *(f16x4*)(out + i4) = o;
  }
}

// ---------------- deformable PSROI pooling (featT is fp16 now) ----------------
template <bool PASS2>
__global__ __launch_bounds__(256) void pool_kernel(const half_t* __restrict__ featT,
                                                   const float* __restrict__ rois,
                                                   const float* __restrict__ om,
                                                   half_t* __restrict__ xout,
                                                   float* __restrict__ out) {
  int bid = blockIdx.x;
  int n = bid / 7, ph = bid % 7;
  int c = threadIdx.x;
  const float* r = rois + n * 5;
  int b = (int)r[0];
  float rsw = rintf(r[1]) * 0.0625f - 0.5f;     // rintf = round-half-even = jnp.round
  float rsh = rintf(r[2]) * 0.0625f - 0.5f;
  float rew = (rintf(r[3]) + 1.0f) * 0.0625f - 0.5f;
  float reh = (rintf(r[4]) + 1.0f) * 0.0625f - 0.5f;
  float roi_w = fmaxf(rew - rsw, 0.1f);
  float roi_h = fmaxf(reh - rsh, 0.1f);
  float bin_h = roi_h / 7.0f;
  float bin_w = roi_w / 7.0f;
  float sub_h = bin_h * 0.25f;
  float sub_w = bin_w * 0.25f;
  const half_t* fb = featT + (size_t)b * (HH * WW) * CC;

  for (int pw = 0; pw < 7; pw++) {
    float tx = 0.0f, ty = 0.0f, mask = 1.0f;
    if (PASS2) {
      int part_h = (int)floorf((float)ph / 7.0f * 7.0f);
      int part_w = (int)floorf((float)pw / 7.0f * 7.0f);
      const float* on = om + n * 147;
      tx = on[part_h * 7 + part_w] * 0.1f;
      ty = on[49 + part_h * 7 + part_w] * 0.1f;
      float mv = on[98 + ph * 7 + pw];
      mask = 1.0f / (1.0f + expf(-mv));
    }
    float hst = (float)ph * bin_h + rsh + ty * roi_h;
    float wst = (float)pw * bin_w + rsw + tx * roi_w;
    float acc = 0.0f;
    int cnt = 0;
    for (int s = 0; s < 16; s++) {
      float h = hst + (float)(s >> 2) * sub_h;
      float w = wst + (float)(s & 3) * sub_w;
      if (w >= -0.5f && w <= (float)WW - 0.5f && h >= -0.5f && h <= (float)HH - 0.5f) {
        float hc = fminf(fmaxf(h, 0.0f), (float)(HH - 1));
        float wc = fminf(fmaxf(w, 0.0f), (float)(WW - 1));
        int h0 = (int)hc;
        int w0 = (int)wc;
        int h1 = min(h0 + 1, HH - 1);
        int w1i = min(w0 + 1, WW - 1);
        float lh = hc - (float)h0;
        float lw = wc - (float)w0;
        float v00 = (float)fb[((size_t)(h0 * WW + w0)) * CC + c];
        float v01 = (float)fb[((size_t)(h0 * WW + w1i)) * CC + c];
        float v10 = (float)fb[((size_t)(h1 * WW + w0)) * CC + c];
        float v11 = (float)fb[((size_t)(h1 * WW + w1i)) * CC + c];
        acc += (v00 * (1.0f - lh) + v10 * lh) * (1.0f - lw) +
               (v01 * (1.0f - lh) + v11 * lh) * lw;
        cnt++;
      }
    }
    float val = (cnt > 0) ? acc / (float)cnt : 0.0f;
    int p = ph * 7 + pw;
    if (PASS2) {
      out[((size_t)(n * CC + c)) * 49 + p] = val * mask;
    } else {
      xout[(size_t)n * KDIM + p * CC + c] = (half_t)val;
    }
  }
}

// ---- split-K fp16 MFMA GEMM: P[z] = A(MxKc) * B(NxKc)^T, tile 64(M)x128(N), BK=64 ----
// grid (M/64, N/128, SK). 4 waves in 2x2; each wave 32x64 via 2x4 of 16x16x32 MFMA.
// Register double-buffer prefetch of next global tile during MFMA phase.
template <int SK>
__global__ __launch_bounds__(256, 4) void gemm_sk(const half_t* __restrict__ A,
                                                  const half_t* __restrict__ B,
                                                  float* __restrict__ P,
                                                  int M, int N, int K) {
  __shared__ half_t As[64 * 72];   // +8 pad: 36-dword row stride -> <=2-way banks (free)
  __shared__ half_t Bs[128 * 72];
  const int m0 = blockIdx.x * 64;
  const int n0 = blockIdx.y * 128;
  const int Kc = K / SK;
  const int kbeg = blockIdx.z * Kc;
  const int tid = threadIdx.x;
  const int lane = tid & 63;
  const int wave = tid >> 6;
  const int wm = (wave & 1) * 32;
  const int wn = (wave >> 1) * 64;
  const int lrow = tid >> 3;          // 0..31
  const int lcol = (tid & 7) * 8;     // 0..56
  const int fr = lane & 15;
  const int fk0 = (lane >> 4) * 8;
  f32x4 acc[2][4] = {};
  const half_t* Ap = A + (size_t)(m0 + lrow) * K + kbeg + lcol;
  const half_t* Bp = B + (size_t)(n0 + lrow) * K + kbeg + lcol;
  uint4 ra[2], rb[4];
  ra[0] = *(const uint4*)(Ap);
  ra[1] = *(const uint4*)(Ap + (size_t)32 * K);
#pragma unroll
  for (int p = 0; p < 4; p++) rb[p] = *(const uint4*)(Bp + (size_t)(32 * p) * K);
  const int iters = Kc >> 6;
  for (int it = 0; it < iters; it++) {
    *(uint4*)&As[lrow * 72 + lcol] = ra[0];
    *(uint4*)&As[(lrow + 32) * 72 + lcol] = ra[1];
#pragma unroll
    for (int p = 0; p < 4; p++) *(uint4*)&Bs[(lrow + 32 * p) * 72 + lcol] = rb[p];
    __syncthreads();
    if (it + 1 < iters) {   // prefetch next tile; completes under the MFMA phase
      int ko = (it + 1) * 64;
      ra[0] = *(const uint4*)(Ap + ko);
      ra[1] = *(const uint4*)(Ap + (size_t)32 * K + ko);
#pragma unroll
      for (int p = 0; p < 4; p++) rb[p] = *(const uint4*)(Bp + (size_t)(32 * p) * K + ko);
    }
#pragma unroll
    for (int ks = 0; ks < 2; ks++) {
      const int fk = fk0 + ks * 32;
      f16x8 af[2], bf[4];
      af[0] = *(const f16x8*)&As[(wm + fr) * 72 + fk];
      af[1] = *(const f16x8*)&As[(wm + 16 + fr) * 72 + fk];
#pragma unroll
      for (int j = 0; j < 4; j++) bf[j] = *(const f16x8*)&Bs[(wn + j * 16 + fr) * 72 + fk];
#pragma unroll
      for (int i = 0; i < 2; i++)
#pragma unroll
        for (int j = 0; j < 4; j++)
          acc[i][j] = __builtin_amdgcn_mfma_f32_16x16x32_f16(af[i], bf[j], acc[i][j], 0, 0, 0);
    }
    __syncthreads();
  }
  // C/D layout: col=lane&15, row=(lane>>4)*4+reg  [measured m89/m91]
  float* Pz = P + (size_t)blockIdx.z * M * N;
  const int orow = m0 + wm + (lane >> 4) * 4;
  const int ocol = n0 + wn + (lane & 15);
#pragma unroll
  for (int i = 0; i < 2; i++)
#pragma unroll
    for (int j = 0; j < 4; j++)
#pragma unroll
      for (int rr = 0; rr < 4; rr++)
        Pz[(size_t)(orow + i * 16 + rr) * N + ocol + j * 16] = acc[i][j][rr];
}

// ---- reduce SK partials + bias (+relu), write fp16 or fp32 ----
template <bool OUT16, bool RELU, int SK>
__global__ __launch_bounds__(256) void reduce_bias(const float* __restrict__ P,
                                                   const float* __restrict__ bias,
                                                   void* __restrict__ out,
                                                   int MN, int N) {
  int i = (blockIdx.x * 256 + threadIdx.x) * 4;
  if (i >= MN) return;
  float4 s = *(const float4*)(P + i);
#pragma unroll
  for (int z = 1; z < SK; z++) {
    float4 t = *(const float4*)(P + (size_t)z * MN + i);
    s.x += t.x; s.y += t.y; s.z += t.z; s.w += t.w;
  }
  float4 bv = *(const float4*)(bias + (i & (N - 1)));
  s.x += bv.x; s.y += bv.y; s.z += bv.z; s.w += bv.w;
  if (RELU) {
    s.x = fmaxf(s.x, 0.0f); s.y = fmaxf(s.y, 0.0f);
    s.z = fmaxf(s.z, 0.0f); s.w = fmaxf(s.w, 0.0f);
  }
  if (OUT16) {
    f16x4 o;
    o[0] = (half_t)s.x; o[1] = (half_t)s.y; o[2] = (half_t)s.z; o[3] = (half_t)s.w;
    *(f16x4*)((half_t*)out + i) = o;
  } else {
    *(float4*)((float*)out + i) = s;
  }
}

// ---------------- fp32 GEMM3: om(N,147) = h2(N,1024) @ w3(147,1024)^T + b3 ----------------
__global__ __launch_bounds__(192) void gemm_small(const float* __restrict__ h2,
                                                  const float* __restrict__ w3,
                                                  const float* __restrict__ b3,
                                                  float* __restrict__ om) {
  __shared__ float hs[FC];
  int n = blockIdx.x;
  for (int k = threadIdx.x; k < FC; k += 192) hs[k] = h2[(size_t)n * FC + k];
  __syncthreads();
  int j = threadIdx.x;
  if (j < 147) {
    float acc = b3[j];
    const float* wr = w3 + (size_t)j * FC;
    for (int k = 0; k < FC; k += 4) {
      float4 wv = *(const float4*)(wr + k);
      acc += hs[k] * wv.x + hs[k + 1] * wv.y + hs[k + 2] * wv.z + hs[k + 3] * wv.w;
    }
    om[n * 147 + j] = acc;
  }
}

extern "C" void kernel_launch(void* const* d_in, const int* in_sizes, int n_in,
                              void* d_out, int out_size, void* d_ws, size_t ws_size,
                              hipStream_t stream) {
  const float* feat = (const float*)d_in[0];
  const float* rois = (const float*)d_in[1];
  const float* w1 = (const float*)d_in[2];
  const float* b1 = (const float*)d_in[3];
  const float* w2 = (const float*)d_in[4];
  const float* b2 = (const float*)d_in[5];
  const float* w3 = (const float*)d_in[6];
  const float* b3 = (const float*)d_in[7];
  float* out = (float*)d_out;
  char* ws = (char*)d_ws;

  // workspace carve (~83.7 MB total)
  half_t* featT = (half_t*)ws;                        // 10,240,000 B
  half_t* xh    = (half_t*)(ws + 10240000);           // 12,845,056 B
  half_t* w1p   = (half_t*)(ws + 23085056);           // 25,690,112 B
  half_t* w2h   = (half_t*)(ws + 48775168);           //  2,097,152 B
  half_t* h1    = (half_t*)(ws + 50872320);           //  1,048,576 B
  float*  h2    = (float*)(ws + 51920896);            //  2,097,152 B
  float*  omb   = (float*)(ws + 54018048);            //    301,056 B
  float*  part  = (float*)(ws + 54319104);            // 29,360,128 B (max of SK=14, SK=8 use)

  const int MN = NROI * FC;  // 524288

  transpose_feat<<<dim3(313, 8, 2), dim3(32, 8), 0, stream>>>(feat, featT);
  permute_w1<<<dim3(1024), dim3(256), 0, stream>>>(w1, w1p);
  convert_f32_f16<<<dim3(1024), dim3(256), 0, stream>>>(w2, w2h, FC * FC);
  pool_kernel<false><<<dim3(NROI * 7), dim3(256), 0, stream>>>(featT, rois, nullptr, xh, nullptr);

  // GEMM1: (512x12544) @ (1024x12544)^T -> SK=14, 896 blocks
  gemm_sk<14><<<dim3(8, 8, 14), dim3(256), 0, stream>>>(xh, w1p, part, NROI, FC, KDIM);
  reduce_bias<true, true, 14><<<dim3(MN / 1024), dim3(256), 0, stream>>>(part, b1, (void*)h1, MN, FC);

  // GEMM2: (512x1024) @ (1024x1024)^T -> SK=8, 512 blocks
  gemm_sk<8><<<dim3(8, 8, 8), dim3(256), 0, stream>>>(h1, w2h, part, NROI, FC, FC);
  reduce_bias<false, true, 8><<<dim3(MN / 1024), dim3(256), 0, stream>>>(part, b2, (void*)h2, MN, FC);

  gemm_small<<<dim3(NROI), dim3(192), 0, stream>>>(h2, w3, b3, omb);
  pool_kernel<true><<<dim3(NROI * 7), dim3(256), 0, stream>>>(featT, rois, omb, nullptr, out);
}